// Round 14
// baseline (255.155 us; speedup 1.0000x reference)
//
#include <hip/hip_runtime.h>
#include <stdint.h>

#define NN 50000
#define DD 128
#define EE 800000
#define LN_EPS 1e-5f
#define SCAN_BLOCKS ((NN + 255) / 256)   // 196
#define ROWS 8                           // nodes per fused block (50000 = 6250 * 8)
#define ASTRIDE 136                      // LDS A stride in bf16 elems
#define FSTRIDE 132                      // LDS fp32 partial stride

#define CH 256                           // edge chunks (one block each)
#define EC (EE / CH)                     // 3125 edges/chunk
#define NP8 50000                        // bytes per chunk hist (u8 per node)
#define NW (NP8 / 4)                     // 12500 u32 words

typedef __attribute__((ext_vector_type(8))) short bf8_t;   // 8 bf16 (MFMA A/B frag)
typedef __attribute__((ext_vector_type(4))) float f32x4;   // MFMA C/D frag

// round-to-nearest-even fp32 -> bf16 bits
static __device__ __forceinline__ unsigned short f2bf(float f) {
    unsigned u = __float_as_uint(f);
    u += 0x7FFFu + ((u >> 16) & 1u);
    return (unsigned short)(u >> 16);
}

#define BF16ACC(u) do { \
    acc[0] += __uint_as_float((u).x << 16); \
    acc[1] += __uint_as_float((u).x & 0xffff0000u); \
    acc[2] += __uint_as_float((u).y << 16); \
    acc[3] += __uint_as_float((u).y & 0xffff0000u); \
    acc[4] += __uint_as_float((u).z << 16); \
    acc[5] += __uint_as_float((u).z & 0xffff0000u); \
    acc[6] += __uint_as_float((u).w << 16); \
    acc[7] += __uint_as_float((u).w & 0xffff0000u); \
} while (0)

// ---------------- chunk histograms: dst + src counted in ONE edge pass (100 KB LDS) ----------------
__global__ __launch_bounds__(256) void hist_kernel(
    const int* __restrict__ src, const int* __restrict__ dst,
    unsigned int* __restrict__ histI, unsigned int* __restrict__ histO) {
    __shared__ unsigned int lhI[NW];   // 50 KB
    __shared__ unsigned int lhO[NW];   // 50 KB
    int tid = threadIdx.x;
    int c = blockIdx.x;
    int e0 = c * EC, e1 = e0 + EC;

    for (int w = tid; w < NW; w += 256) { lhI[w] = 0; lhO[w] = 0; }
    __syncthreads();
    for (int e = e0 + tid; e < e1; e += 256) {
        int d = dst[e];
        int s = src[e];
        atomicAdd(&lhI[d >> 2], 1u << ((d & 3) * 8));
        atomicAdd(&lhO[s >> 2], 1u << ((s & 3) * 8));
    }
    __syncthreads();
    {
        unsigned int* oi = histI + (size_t)c * NW;
        unsigned int* oo = histO + (size_t)c * NW;
        for (int w = tid; w < NW; w += 256) { oi[w] = lhI[w]; oo[w] = lhO[w]; }
    }
}

// ---------------- sum chunk hists -> cntI/choff(in-place)/iso/isi/bsum ----------------
__global__ __launch_bounds__(256) void sum_kernel(
    unsigned char* __restrict__ histI8,          // in-place -> choff8
    const unsigned char* __restrict__ histO8,
    int* __restrict__ cntI, float* __restrict__ iso, float* __restrict__ isi,
    int* __restrict__ bsum) {
    __shared__ int s[256];
    int tid = threadIdx.x;
    int n = blockIdx.x * 256 + tid;

    int ci = 0, co = 0;
    if (n < NN) {
#pragma unroll 8
        for (int c = 0; c < CH; c++) {
            size_t idx = (size_t)c * NP8 + n;
            unsigned char v = histI8[idx];
            histI8[idx] = (unsigned char)ci;   // choff8[c][n] = prefix (max in-deg << 256)
            ci += v;
            co += histO8[idx];
        }
        iso[n] = rsqrtf(fmaxf((float)co, 1.0f));
        isi[n] = rsqrtf(fmaxf((float)ci, 1.0f));
        cntI[n] = ci;
    }
    s[tid] = (n < NN) ? ci : 0;
    __syncthreads();
    for (int off = 128; off > 0; off >>= 1) {
        if (tid < off) s[tid] += s[tid + off];
        __syncthreads();
    }
    if (tid == 0) bsum[blockIdx.x] = s[0];
}

// ---------------- rowptr (local bsum prefix) + feature cast (hb1 = bf16(feat*iso)) ----------------
__global__ __launch_bounds__(256) void scanC_kernel(
    const int* __restrict__ cnt, const int* __restrict__ bsum,
    int* __restrict__ rowptr,
    const float* __restrict__ feat, const float* __restrict__ iso,
    unsigned short* __restrict__ hb) {
    __shared__ int s[256];
    __shared__ int base_s;
    __shared__ float iso_s[256];
    int tid = threadIdx.x;
    int i = blockIdx.x * 256 + tid;

    int bv = (tid < SCAN_BLOCKS && tid < blockIdx.x) ? bsum[tid] : 0;
    s[tid] = bv;
    __syncthreads();
    for (int off = 128; off > 0; off >>= 1) {
        if (tid < off) s[tid] += s[tid + off];
        __syncthreads();
    }
    if (tid == 0) base_s = s[0];
    __syncthreads();
    int base = base_s;

    iso_s[tid] = (i < NN) ? iso[i] : 1.f;
    __syncthreads();

    int v = (i < NN) ? cnt[i] : 0;
    s[tid] = v;
    __syncthreads();
    for (int off = 1; off < 256; off <<= 1) {
        int t = (tid >= off) ? s[tid - off] : 0;
        __syncthreads();
        s[tid] += t;
        __syncthreads();
    }
    if (i < NN) rowptr[i] = base + s[tid] - v;  // exclusive
    if (blockIdx.x == 0 && tid == 0) rowptr[NN] = EE;

    // cast this block's 256 rows: 8 rows x 32 lanes (coalesced float4)
    int rr = tid >> 5;
    int q = tid & 31;
    int row0 = blockIdx.x * 256;
#pragma unroll 4
    for (int it = 0; it < 32; it++) {
        int r = it * 8 + rr;
        int row = row0 + r;
        if (row < NN) {
            float sc = iso_s[r];
            float4 fv = ((const float4*)feat)[(size_t)row * 32 + q];
            ushort4 o;
            o.x = f2bf(fv.x * sc); o.y = f2bf(fv.y * sc);
            o.z = f2bf(fv.z * sc); o.w = f2bf(fv.w * sc);
            ((ushort4*)hb)[(size_t)row * 32 + q] = o;
        }
    }
}

// ---------------- CSR fill: one block per chunk; choff slice + recomputed epos in LDS ----------
__global__ __launch_bounds__(256) void fill_kernel(
    const int* __restrict__ src, const int* __restrict__ dst,
    const unsigned char* __restrict__ choff8,
    const int* __restrict__ rowptr, int* __restrict__ csr,
    const float* __restrict__ W1, const float* __restrict__ W2,
    unsigned short* __restrict__ wbt1, unsigned short* __restrict__ wbt2) {
    __shared__ unsigned int lh[NW];        // 50 KB counting
    __shared__ unsigned char lco[NP8];     // 50 KB choff slice
    int tid = threadIdx.x;
    int c = blockIdx.x;
    int e0 = c * EC, e1 = e0 + EC;

    {
        const unsigned int* ci = (const unsigned int*)(choff8 + (size_t)c * NP8);
        for (int w = tid; w < NW; w += 256) { lh[w] = 0; ((unsigned int*)lco)[w] = ci[w]; }
    }
    __syncthreads();
    for (int e = e0 + tid; e < e1; e += 256) {
        int d = dst[e];
        int f = (d & 3) * 8;
        unsigned old = atomicAdd(&lh[d >> 2], 1u << f);
        int epos = (int)((old >> f) & 0xffu);
        csr[rowptr[d] + (int)lco[d] + epos] = src[e];
    }
    // first 128 blocks also produce wbt[n][k] = bf16(W[k][n])
    if (c < 128) {
        int idx = (c & 63) * 256 + tid;    // 0..16383 = k*128+n
        const float* W = (c < 64) ? W1 : W2;
        unsigned short* wt = (c < 64) ? wbt1 : wbt2;
        int k = idx >> 7, n = idx & 127;
        wt[n * 128 + k] = f2bf(W[idx]);
    }
}

// ---------------- fused: 2-way edge-split gather -> bf16 LDS -> MFMA -> LN -> ReLU ----------
// ROWS=8, 6250 blocks, 256 threads = 16 subgroups of 16 lanes; subgroup sg owns row sg>>1,
// edge-half sg&1 (stride-2 interleave) — halves the per-row latency chain vs round 13.
// fp32 partials combined in LDS; MFMA A-tile zero-padded to 16 rows (rows 8-15 discarded).
template <int OUTMODE>
__global__ __launch_bounds__(256) void fused_layer(
    const unsigned short* __restrict__ hb, const int* __restrict__ csr,
    const int* __restrict__ rowptr, const float* __restrict__ isi,
    const float* __restrict__ iso,
    const unsigned short* __restrict__ wbt, const float* __restrict__ b,
    const float* __restrict__ g, const float* __restrict__ be,
    float* __restrict__ outf, unsigned short* __restrict__ outb) {
    __shared__ float Af[2][ROWS][FSTRIDE];          // 8448 B fp32 partials
    __shared__ unsigned short Asb[16][ASTRIDE];     // 4352 B MFMA A tile (rows 8-15 zero)
    __shared__ float redS[4][16], redSS[4][16];     // 512 B

    int tid = threadIdx.x;
    int node0 = blockIdx.x * ROWS;
    int w = tid >> 6;            // wave 0..3
    int lane = tid & 63;
    int quad = lane >> 4;        // 0..3
    int l = lane & 15;           // 0..15

    // zero the MFMA A tile (rows 0-7 are overwritten by the pack stage; 8-15 stay zero)
    for (int i = tid; i < 16 * (ASTRIDE / 8); i += 256)
        *(uint4*)&Asb[i >> 4][(i & 15) * 8] = (uint4){0, 0, 0, 0};

    // ---- phase 1: gather (subgroup sg = tid>>4: row sg>>1, edge-half sg&1) ----
    {
        int sg = tid >> 4;
        int r = sg >> 1;
        int h = sg & 1;
        int n = node0 + r;
        float acc[8];
#pragma unroll
        for (int i = 0; i < 8; i++) acc[i] = 0.f;
        int beg = rowptr[n];
        int end = rowptr[n + 1];
        for (int j = beg + h; j < end; j += 16) {
            uint4 u[8];
            unsigned m[8];
#pragma unroll
            for (int i = 0; i < 8; i++) {
                int t = j + 2 * i;
                int tc = (t < end) ? t : (end - 1);
                m[i] = (t < end) ? 0xffffffffu : 0u;
                int s = csr[tc];
                u[i] = ((const uint4*)(hb + (size_t)s * DD))[l];
            }
#pragma unroll
            for (int i = 0; i < 8; i++) {
                uint4 v = u[i];
                v.x &= m[i]; v.y &= m[i]; v.z &= m[i]; v.w &= m[i];
                BF16ACC(v);
            }
        }
        *(float4*)&Af[h][r][l * 8]     = make_float4(acc[0], acc[1], acc[2], acc[3]);
        *(float4*)&Af[h][r][l * 8 + 4] = make_float4(acc[4], acc[5], acc[6], acc[7]);
    }
    __syncthreads();

    // ---- combine halves + pack bf16 (128 workers) ----
    if (tid < 128) {
        int r = tid >> 4;
        int li = tid & 15;
        float4 a0 = *(float4*)&Af[0][r][li * 8];
        float4 a1 = *(float4*)&Af[0][r][li * 8 + 4];
        float4 b0 = *(float4*)&Af[1][r][li * 8];
        float4 b1 = *(float4*)&Af[1][r][li * 8 + 4];
        uint4 pk;
        pk.x = (unsigned)f2bf(a0.x + b0.x) | ((unsigned)f2bf(a0.y + b0.y) << 16);
        pk.y = (unsigned)f2bf(a0.z + b0.z) | ((unsigned)f2bf(a0.w + b0.w) << 16);
        pk.z = (unsigned)f2bf(a1.x + b1.x) | ((unsigned)f2bf(a1.y + b1.y) << 16);
        pk.w = (unsigned)f2bf(a1.z + b1.z) | ((unsigned)f2bf(a1.w + b1.w) << 16);
        *(uint4*)&Asb[r][li * 8] = pk;
    }
    __syncthreads();

    // ---- phase 2: MFMA GEMM (16-row tile, rows 8-15 zero; wave w -> cols [w*32, +32)) ----
    bf8_t af[4];
#pragma unroll
    for (int kb = 0; kb < 4; kb++)
        af[kb] = *(bf8_t*)&Asb[l][kb * 32 + quad * 8];

    f32x4 acc[2];
#pragma unroll
    for (int tc = 0; tc < 2; tc++) acc[tc] = (f32x4){0.f, 0.f, 0.f, 0.f};

#pragma unroll
    for (int tc = 0; tc < 2; tc++) {
        int n = w * 32 + tc * 16 + l;   // output column
#pragma unroll
        for (int kb = 0; kb < 4; kb++) {
            bf8_t bfr = *(const bf8_t*)&wbt[(size_t)n * 128 + kb * 32 + quad * 8];
            acc[tc] = __builtin_amdgcn_mfma_f32_16x16x32_bf16(af[kb], bfr, acc[tc], 0, 0, 0);
        }
    }

    // ---- epilogue: *isi, +b, LN, ReLU, store (valid rows: quad*4+i < 8) ----
    float bb[2], ggv[2], bev[2];
    int cbase = w * 32 + l;
#pragma unroll
    for (int tc = 0; tc < 2; tc++) {
        int c = cbase + tc * 16;
        bb[tc] = b[c]; ggv[tc] = g[c]; bev[tc] = be[c];
    }

    float s[4], ss[4];
#pragma unroll
    for (int i = 0; i < 4; i++) {
        int r = quad * 4 + i;
        float isin = (r < ROWS) ? isi[node0 + r] : 0.f;
        s[i] = 0.f; ss[i] = 0.f;
#pragma unroll
        for (int tc = 0; tc < 2; tc++) {
            float v = acc[tc][i] * isin + bb[tc];
            acc[tc][i] = v;
            s[i] += v; ss[i] += v * v;
        }
    }
#pragma unroll
    for (int i = 0; i < 4; i++) {
#pragma unroll
        for (int m = 1; m <= 8; m <<= 1) {
            s[i] += __shfl_xor(s[i], m);
            ss[i] += __shfl_xor(ss[i], m);
        }
    }
    if (l == 0) {
#pragma unroll
        for (int i = 0; i < 4; i++) {
            redS[w][quad * 4 + i] = s[i];
            redSS[w][quad * 4 + i] = ss[i];
        }
    }
    __syncthreads();

#pragma unroll
    for (int i = 0; i < 4; i++) {
        int r = quad * 4 + i;
        if (r < ROWS) {
            float S  = redS[0][r] + redS[1][r] + redS[2][r] + redS[3][r];
            float SS = redSS[0][r] + redSS[1][r] + redSS[2][r] + redSS[3][r];
            float mu = S * (1.f / 128.f);
            float var = SS * (1.f / 128.f) - mu * mu;
            float rstd = rsqrtf(var + LN_EPS);
            int n = node0 + r;
            float isov = (OUTMODE == 1) ? iso[n] : 0.f;
            size_t base = (size_t)n * DD;
#pragma unroll
            for (int tc = 0; tc < 2; tc++) {
                float o = fmaxf((acc[tc][i] - mu) * rstd * ggv[tc] + bev[tc], 0.f);
                int c = cbase + tc * 16;
                if (OUTMODE == 0) {
                    outf[base + c] = o;
                } else {
                    outb[base + c] = f2bf(o * isov);
                }
            }
        }
    }
}

static inline char* alignp(char* p, size_t a) {
    return (char*)(((uintptr_t)p + a - 1) & ~(uintptr_t)(a - 1));
}

extern "C" void kernel_launch(void* const* d_in, const int* in_sizes, int n_in,
                              void* d_out, int out_size, void* d_ws, size_t ws_size,
                              hipStream_t stream) {
    const float* features = (const float*)d_in[0];
    const int*   src      = (const int*)d_in[1];
    const int*   dst      = (const int*)d_in[2];
    const float* W1  = (const float*)d_in[3];
    const float* b1  = (const float*)d_in[4];
    const float* g1  = (const float*)d_in[5];
    const float* be1 = (const float*)d_in[6];
    const float* W2  = (const float*)d_in[7];
    const float* b2  = (const float*)d_in[8];
    const float* g2  = (const float*)d_in[9];
    const float* be2 = (const float*)d_in[10];
    float* out = (float*)d_out;

    // workspace layout (256B-aligned slices)
    char* p = (char*)d_ws;
    int* cntI = (int*)p;                 p = alignp(p + NN * 4, 256);
    int* rowptr = (int*)p;               p = alignp(p + (NN + 1) * 4, 256);
    int* bsum = (int*)p;                 p = alignp(p + SCAN_BLOCKS * 4, 256);
    int* csr = (int*)p;                  p = alignp(p + (size_t)EE * 4, 256);
    float* iso = (float*)p;              p = alignp(p + NN * 4, 256);
    float* isi = (float*)p;              p = alignp(p + NN * 4, 256);
    unsigned short* hb1 = (unsigned short*)p;  p = alignp(p + (size_t)NN * DD * 2, 256);
    unsigned short* hb2 = (unsigned short*)p;  p = alignp(p + (size_t)NN * DD * 2, 256);
    unsigned short* wbt1 = (unsigned short*)p; p = alignp(p + DD * DD * 2, 256);
    unsigned short* wbt2 = (unsigned short*)p; p = alignp(p + DD * DD * 2, 256);

    // Aliases (CH*NP8 = 12,800,000 B = exactly NN*DD*2):
    //  histI8 -> hb2: choff dead after fill_kernel; fused<1> writes hb2 after fill.  OK
    //  histO8 -> hb1: histO dead after sum_kernel; scanC writes hb1 (cast) after sum. OK
    unsigned char* histI8 = (unsigned char*)hb2;
    unsigned char* histO8 = (unsigned char*)hb1;

    hist_kernel<<<CH, 256, 0, stream>>>(src, dst,
                                        (unsigned int*)histI8, (unsigned int*)histO8);
    sum_kernel<<<SCAN_BLOCKS, 256, 0, stream>>>(histI8, histO8, cntI, iso, isi, bsum);
    scanC_kernel<<<SCAN_BLOCKS, 256, 0, stream>>>(cntI, bsum, rowptr, features, iso, hb1);
    fill_kernel<<<CH, 256, 0, stream>>>(src, dst, histI8, rowptr, csr,
                                        W1, W2, wbt1, wbt2);

    const int fblocks = NN / ROWS;  // 6250 exactly
    // layer 1: hb1 -> hb2 (bf16, iso-prescaled)
    fused_layer<1><<<fblocks, 256, 0, stream>>>(hb1, csr, rowptr, isi, iso,
                                                wbt1, b1, g1, be1, nullptr, hb2);
    // layer 2: hb2 -> out (fp32)
    fused_layer<0><<<fblocks, 256, 0, stream>>>(hb2, csr, rowptr, isi, iso,
                                                wbt2, b2, g2, be2, out, nullptr);
}